// Round 24
// baseline (304.302 us; speedup 1.0000x reference)
//
#include <hip/hip_runtime.h>

typedef unsigned short u16;
typedef unsigned int u32;
typedef __attribute__((ext_vector_type(8))) short bf16x8;
typedef __attribute__((ext_vector_type(4))) float f32x4;
typedef __attribute__((ext_vector_type(4))) u32 u32x4;

#define N_SEQ 256
#define L_RES 384
#define DM 256
#define NH 8
#define DH 32
#define M_ROWS (N_SEQ*L_RES)   // 98304
#define PANEL 8192             // N_SEQ*DH elements per (l,h) panel

// x / weights: swizzled fragment layout swz(i,k) = ((i>>4)*32+(k>>3))*128+(i&15)*8+(k&7)
// q/k/v/g/ao: per-(l,h) panels [l][h][n][d], each 16KB contiguous.

__device__ __forceinline__ u16 f2b(float f){
    unsigned u = __builtin_bit_cast(unsigned, f);
    u = u + 0x7fffu + ((u >> 16) & 1u);
    return (u16)(u >> 16);
}
__device__ __forceinline__ float b2f(u16 b){
    unsigned u = ((unsigned)b) << 16;
    return __builtin_bit_cast(float, u);
}
// pack two floats -> two bf16 in a u32 (round-to-nearest, ties up)
__device__ __forceinline__ u32 pk2(float lo, float hi){
    u32 a = (__builtin_bit_cast(u32, lo) + 0x8000u) >> 16;
    u32 b = (__builtin_bit_cast(u32, hi) + 0x8000u) & 0xffff0000u;
    return a | b;
}
// LDS bank-conflict XOR swizzle for B tiles (u16 units, keeps 16B alignment)
__device__ __forceinline__ int swzB(int a){
    return a ^ (((a>>6)&7)<<3);
}

// ---------------- Kernel 0: weights f32 -> bf16 swizzled ----------------
__global__ __launch_bounds__(256) void k_wcvt(const float* __restrict__ wq,
        const float* __restrict__ wk, const float* __restrict__ wv,
        const float* __restrict__ wg, const float* __restrict__ wo,
        u16* __restrict__ wsw){
    const int mat = blockIdx.x >> 6;
    const float* W = (mat==0)?wq:(mat==1)?wk:(mat==2)?wv:(mat==3)?wg:wo;
    const int r = ((blockIdx.x & 63)*256 + threadIdx.x)*4;
    const int col = r >> 8, k0 = r & 255;
    float4 f = *(const float4*)&W[r];
    ushort4 o;
    o.x = f2b(f.x); o.y = f2b(f.y); o.z = f2b(f.z); o.w = f2b(f.w);
    const int off = ((col>>4)*32 + (k0>>3))*128 + (col&15)*8 + (k0&7);
    *(ushort4*)&wsw[mat*65536 + off] = o;
}

// ---------------- Kernel 1: LayerNorm -> bf16 x (A-swizzled, direct store) ----------------
__global__ __launch_bounds__(256) void k_ln(const float* __restrict__ msa,
        const float* __restrict__ lnw, const float* __restrict__ lnb,
        u16* __restrict__ xo){
    const int tid = threadIdx.x;
    const int r16 = tid >> 4, lane16 = tid & 15;
    const size_t row = (size_t)blockIdx.x*16 + r16;
    const float4* src = (const float4*)(msa + row*DM + lane16*16);
    float4 a[4];
    float s = 0.f, ss = 0.f;
    #pragma unroll
    for(int j=0;j<4;j++){
        a[j] = src[j];
        s  += a[j].x + a[j].y + a[j].z + a[j].w;
        ss += a[j].x*a[j].x + a[j].y*a[j].y + a[j].z*a[j].z + a[j].w*a[j].w;
    }
    #pragma unroll
    for(int m=1;m<16;m<<=1){ s += __shfl_xor(s,m); ss += __shfl_xor(ss,m); }
    const float mu  = s*(1.f/DM);
    const float inv = rsqrtf(ss*(1.f/DM) - mu*mu + 1e-5f);
    const float4* wv4 = (const float4*)(lnw + lane16*16);
    const float4* bv4 = (const float4*)(lnb + lane16*16);
    u32 pk[8];
    #pragma unroll
    for(int j=0;j<4;j++){
        float4 w = wv4[j], b = bv4[j];
        float e0 = (a[j].x-mu)*inv*w.x + b.x;
        float e1 = (a[j].y-mu)*inv*w.y + b.y;
        float e2 = (a[j].z-mu)*inv*w.z + b.z;
        float e3 = (a[j].w-mu)*inv*w.w + b.w;
        pk[j*2]   = (u32)f2b(e0) | ((u32)f2b(e1)<<16);
        pk[j*2+1] = (u32)f2b(e2) | ((u32)f2b(e3)<<16);
    }
    u16* base = xo + (size_t)blockIdx.x*4096 + lane16*256 + r16*8;
    *(uint4*)base       = *(uint4*)&pk[0];
    *(uint4*)(base+128) = *(uint4*)&pk[4];
}

// ---------------- Kernel 2: fused Q/K/V/G projections -> [l][h][n][d] panels ----------------
// Block = (by, mat). The wave's 8 x-fragments are loaded into registers ONCE,
// then reused across the mat's four 64-col weight tiles (staged sequentially
// in one 32KB LDS buffer). x global reads /4 vs per-cb blocks.
__global__ __launch_bounds__(512) void k_qkvg(const u16* __restrict__ x,
        const u16* __restrict__ wsw, const float* __restrict__ bg,
        u16* __restrict__ qo, u16* __restrict__ ko,
        u16* __restrict__ vo, u16* __restrict__ go){
    __shared__ __align__(16) u16 Bs[16384];          // 32KB weight tile (per cg)
    const int by = blockIdx.x, mat = blockIdx.y;
    const int tid = threadIdx.x;
    const int w = tid>>6, lane = tid&63, l15 = lane&15, lq = lane>>4;
    const u16* xa = x + ((size_t)by*8 + w)*4096;      // wave's 16 rows (1 group)
    bf16x8 xf[8];
    #pragma unroll
    for(int kk=0;kk<8;kk++)
        xf[kk] = *(const bf16x8*)&xa[(kk*4+lq)*128 + l15*8];
    const float scaling = 0.17677669529663687f * 1.44269504088896f; // /sqrt(d)*log2e
    u16* O = (mat==0)?qo:(mat==1)?ko:(mat==2)?vo:go;
    const int n0 = by/3, l0 = (by%3)*128;
    const int l = l0 + w*16 + l15;                    // this lane's x-row (l coord)
    #pragma unroll 1
    for(int cg=0; cg<4; ++cg){
        const u16* wt = wsw + mat*65536 + cg*16384;
        __syncthreads();                              // prior tile reads complete
        #pragma unroll
        for(int i=0;i<4;i++)
            *(uint4*)&Bs[swzB(i*4096 + tid*8)] = *(const uint4*)&wt[i*4096 + tid*8];
        __syncthreads();
        f32x4 acc[4] = {};
        #pragma unroll
        for(int kk=0;kk<8;kk++){
            #pragma unroll
            for(int nt=0;nt<4;nt++){
                bf16x8 b = *(const bf16x8*)&Bs[swzB(nt*4096 + (kk*4+lq)*128 + l15*8)];
                acc[nt] = __builtin_amdgcn_mfma_f32_16x16x32_bf16(b,xf[kk],acc[nt],0,0,0);
            }
        }
        #pragma unroll
        for(int nt=0;nt<4;nt++){
            const int c = cg*64 + nt*16 + lq*4;       // 4 consecutive weight cols
            float v0 = acc[nt][0], v1 = acc[nt][1];
            float v2 = acc[nt][2], v3 = acc[nt][3];
            if(mat==0){ v0*=scaling; v1*=scaling; v2*=scaling; v3*=scaling; }
            else if(mat==3){
                const float4 bgv = *(const float4*)&bg[c];
                v0 = 1.f/(1.f+__expf(-(v0+bgv.x)));
                v1 = 1.f/(1.f+__expf(-(v1+bgv.y)));
                v2 = 1.f/(1.f+__expf(-(v2+bgv.z)));
                v3 = 1.f/(1.f+__expf(-(v3+bgv.w)));
            }
            uint2 ov;
            ov.x = pk2(v0, v1);
            ov.y = pk2(v2, v3);
            const int h2 = c >> 5, d = c & 31;
            *(uint2*)&O[((size_t)l*NH + h2)*PANEL + n0*32 + d] = ov;
        }
    }
}

// ---------------- Kernel 3: column attention + gate ----------------
// 8 waves x 2 interleaved 16-row streams (validated swapped-operand core).
// launch_bounds min-waves relaxed 4->2: the 2-stream state needs >64 VGPRs;
// the old cap forced scratch spills (VGPR pinned at exactly 64).
__global__ __launch_bounds__(512, 2) void k_attn(const u16* __restrict__ q,
        const u16* __restrict__ k, const u16* __restrict__ v,
        const u16* __restrict__ g, u16* __restrict__ ao){
    __shared__ __align__(16) u16 KFs[8192];   // K fragment-linear: 256 keys x 32 d
    __shared__ __align__(16) u16 VFs[8192];   // V^T fragment-linear, keys permuted
    const int h = blockIdx.x, l = blockIdx.y;
    const int tid = threadIdx.x;
    const size_t pbase = ((size_t)l*NH + h)*PANEL;
    const u16* kp = k + pbase;
    const u16* vp = v + pbase;
    #pragma unroll
    for(int j=0;j<2;j++){
        const int u = j*512 + tid;          // uint4 index 0..1023
        const int key = u>>2, dblk = u&3;   // d0 = dblk*8
        const uint4 tk = *(const uint4*)&kp[u*8];
        *(uint4*)&KFs[((key>>4)*4 + dblk)*128 + (key&15)*8] = tk;
        const uint4 tv = *(const uint4*)&vp[u*8];
        const int T = key>>4, gg = (key>>2)&3, r = key&3;
        const int pkey = (T>>1)*32 + ((gg&2)|(T&1))*8 + r + (((gg^T)&1)<<2);
        const int plo = (pkey>>3)*128 + (pkey&7);
        const u32 wv_[4] = {tv.x, tv.y, tv.z, tv.w};
        #pragma unroll
        for(int wd=0; wd<4; wd++){
            const int d_lo = dblk*8 + wd*2, d_hi = d_lo+1;
            VFs[((d_lo)>>4)*4096 + plo + ((d_lo)&15)*8] = (u16)(wv_[wd]&0xffff);
            VFs[((d_hi)>>4)*4096 + plo + ((d_hi)&15)*8] = (u16)(wv_[wd]>>16);
        }
    }
    __syncthreads();
    const int w = tid>>6, lane = tid&63;
    const int l15 = lane&15, lq = lane>>4;
    const int lodd = lq & 1;
    const u16* qp = q + pbase;
    const u16* gp = g + pbase;
    u16* aop = ao + pbase;
    const int q0a = w*32, q0b = w*32 + 16;
    const bf16x8 bqA = *(const bf16x8*)&qp[(q0a+l15)*32 + lq*8];
    const bf16x8 bqB = *(const bf16x8*)&qp[(q0b+l15)*32 + lq*8];
    float mA = -1e30f, spA = 0.f;
    float mB = -1e30f, spB = 0.f;
    f32x4 oaccA[2] = {}, oaccB[2] = {};
    #pragma unroll
    for(int ch=0; ch<4; ch++){
        f32x4 sA[4], sB[4];
        #pragma unroll
        for(int tt=0;tt<4;tt++){
            bf16x8 ak = *(const bf16x8*)&KFs[((ch*4+tt)*4 + lq)*128 + l15*8];
            f32x4 z = {};
            sA[tt] = __builtin_amdgcn_mfma_f32_16x16x32_bf16(ak,bqA,z,0,0,0);
            f32x4 z2 = {};
            sB[tt] = __builtin_amdgcn_mfma_f32_16x16x32_bf16(ak,bqB,z2,0,0,0);
        }
        float cmA = fmaxf(fmaxf(fmaxf(sA[0][0],sA[0][1]),fmaxf(sA[0][2],sA[0][3])),
                   fmaxf(fmaxf(fmaxf(sA[1][0],sA[1][1]),fmaxf(sA[1][2],sA[1][3])),
                   fmaxf(fmaxf(fmaxf(sA[2][0],sA[2][1]),fmaxf(sA[2][2],sA[2][3])),
                         fmaxf(fmaxf(sA[3][0],sA[3][1]),fmaxf(sA[3][2],sA[3][3])))));
        float cmB = fmaxf(fmaxf(fmaxf(sB[0][0],sB[0][1]),fmaxf(sB[0][2],sB[0][3])),
                   fmaxf(fmaxf(fmaxf(sB[1][0],sB[1][1]),fmaxf(sB[1][2],sB[1][3])),
                   fmaxf(fmaxf(fmaxf(sB[2][0],sB[2][1]),fmaxf(sB[2][2],sB[2][3])),
                         fmaxf(fmaxf(sB[3][0],sB[3][1]),fmaxf(sB[3][2],sB[3][3])))));
        cmA = fmaxf(cmA, __shfl_xor(cmA,16));
        cmB = fmaxf(cmB, __shfl_xor(cmB,16));
        cmA = fmaxf(cmA, __shfl_xor(cmA,32));
        cmB = fmaxf(cmB, __shfl_xor(cmB,32));
        const float mnA = fmaxf(mA, cmA), mnB = fmaxf(mB, cmB);
        const float scA = exp2f(mA - mnA), scB = exp2f(mB - mnB);
        mA = mnA; mB = mnB;
        float csA = 0.f, csB = 0.f;
        #pragma unroll
        for(int tt=0;tt<4;tt++){
            #pragma unroll
            for(int rg=0;rg<4;rg++){
                float eA = exp2f(sA[tt][rg] - mnA);
                float eB = exp2f(sB[tt][rg] - mnB);
                sA[tt][rg] = eA; csA += eA;
                sB[tt][rg] = eB; csB += eB;
            }
        }
        spA = spA*scA + csA;
        spB = spB*scB + csB;
        #pragma unroll
        for(int i=0;i<4;i++){ oaccA[0][i]*=scA; oaccA[1][i]*=scA; oaccB[0][i]*=scB; oaccB[1][i]*=scB; }
        #pragma unroll
        for(int half=0; half<2; half++){
            const int mwin = ch*2 + half;
            u32 eA0 = pk2(sA[half*2][0],   sA[half*2][1]);
            u32 eA1 = pk2(sA[half*2][2],   sA[half*2][3]);
            u32 oA0 = pk2(sA[half*2+1][0], sA[half*2+1][1]);
            u32 oA1 = pk2(sA[half*2+1][2], sA[half*2+1][3]);
            u32 eB0 = pk2(sB[half*2][0],   sB[half*2][1]);
            u32 eB1 = pk2(sB[half*2][2],   sB[half*2][3]);
            u32 oB0 = pk2(sB[half*2+1][0], sB[half*2+1][1]);
            u32 oB1 = pk2(sB[half*2+1][2], sB[half*2+1][3]);
            u32 ownA0 = lodd ? oA0 : eA0,  ownA1 = lodd ? oA1 : eA1;
            u32 sndA0 = lodd ? eA0 : oA0,  sndA1 = lodd ? eA1 : oA1;
            u32 ownB0 = lodd ? oB0 : eB0,  ownB1 = lodd ? oB1 : eB1;
            u32 sndB0 = lodd ? eB0 : oB0,  sndB1 = lodd ? eB1 : oB1;
            u32 rcA0 = (u32)__shfl_xor((int)sndA0, 16);
            u32 rcB0 = (u32)__shfl_xor((int)sndB0, 16);
            u32 rcA1 = (u32)__shfl_xor((int)sndA1, 16);
            u32 rcB1 = (u32)__shfl_xor((int)sndB1, 16);
            u32x4 pwA = {ownA0, ownA1, rcA0, rcA1};
            u32x4 pwB = {ownB0, ownB1, rcB0, rcB1};
            bf16x8 pfA = __builtin_bit_cast(bf16x8, pwA);
            bf16x8 pfB = __builtin_bit_cast(bf16x8, pwB);
            #pragma unroll
            for(int nt=0;nt<2;nt++){
                bf16x8 av = *(const bf16x8*)&VFs[(nt*32 + mwin*4 + lq)*128 + l15*8];
                oaccA[nt] = __builtin_amdgcn_mfma_f32_16x16x32_bf16(av,pfA,oaccA[nt],0,0,0);
                oaccB[nt] = __builtin_amdgcn_mfma_f32_16x16x32_bf16(av,pfB,oaccB[nt],0,0,0);
            }
        }
    }
    spA += __shfl_xor(spA, 16);
    spB += __shfl_xor(spB, 16);
    spA += __shfl_xor(spA, 32);
    spB += __shfl_xor(spB, 32);
    const float rinvA = 1.f/spA, rinvB = 1.f/spB;
    const int qnA = q0a + l15, qnB = q0b + l15;
    #pragma unroll
    for(int nt=0;nt<2;nt++){
        const int c = nt*16 + lq*4;
        const uint2 glA = *(const uint2*)&gp[qnA*32 + c];
        const uint2 glB = *(const uint2*)&gp[qnB*32 + c];
        uint2 ovA, ovB;
        ovA.x = pk2(b2f((u16)(glA.x&0xffff))*oaccA[nt][0]*rinvA,
                    b2f((u16)(glA.x>>16))   *oaccA[nt][1]*rinvA);
        ovA.y = pk2(b2f((u16)(glA.y&0xffff))*oaccA[nt][2]*rinvA,
                    b2f((u16)(glA.y>>16))   *oaccA[nt][3]*rinvA);
        ovB.x = pk2(b2f((u16)(glB.x&0xffff))*oaccB[nt][0]*rinvB,
                    b2f((u16)(glB.x>>16))   *oaccB[nt][1]*rinvB);
        ovB.y = pk2(b2f((u16)(glB.y&0xffff))*oaccB[nt][2]*rinvB,
                    b2f((u16)(glB.y>>16))   *oaccB[nt][3]*rinvB);
        *(uint2*)&aop[qnA*32 + c] = ovA;
        *(uint2*)&aop[qnB*32 + c] = ovB;
    }
}

// ---------------- Kernel 4: output projection (512 thr / 8 waves x 16 rows) ----------------
__global__ __launch_bounds__(512) void k_out(const u16* __restrict__ a,
        const u16* __restrict__ wsw, const float* __restrict__ bo,
        float* __restrict__ out){
    __shared__ __align__(16) u16 Bs[16384];
    const int cb = blockIdx.x, nb = blockIdx.y, l = blockIdx.z;
    const int c0 = cb*64;
    const int tid = threadIdx.x;
    const u16* wt = wsw + 4*65536 + (c0>>4)*4096;
    #pragma unroll
    for(int i=0;i<4;i++)
        *(uint4*)&Bs[swzB(i*4096 + tid*8)] = *(const uint4*)&wt[i*4096 + tid*8];
    const int w = tid>>6, lane = tid&63, l15 = lane&15, lq = lane>>4;
    const int n0 = nb*128 + w*16;
    const size_t lbase = (size_t)l*NH*PANEL;
    bf16x8 af[8];
    #pragma unroll
    for(int kk=0;kk<8;kk++)
        af[kk] = *(const bf16x8*)&a[lbase + (size_t)kk*PANEL + (n0 + l15)*32 + lq*8];
    __syncthreads();
    f32x4 acc[4] = {};
    #pragma unroll
    for(int kk=0;kk<8;kk++){   // k = kk*32 + lq*8 -> h = kk, d = lq*8
        #pragma unroll
        for(int nt=0;nt<4;nt++){
            bf16x8 b = *(const bf16x8*)&Bs[swzB(nt*4096 + (kk*4+lq)*128 + l15*8)];
            acc[nt] = __builtin_amdgcn_mfma_f32_16x16x32_bf16(af[kk],b,acc[nt],0,0,0);
        }
    }
    #pragma unroll
    for(int nt=0;nt<4;nt++){
        const int c = c0 + nt*16 + l15;
        const float bov = bo[c];
        #pragma unroll
        for(int rg=0;rg<4;rg++){
            const int n = n0 + lq*4 + rg;
            out[((size_t)n*L_RES + l)*DM + c] = acc[nt][rg] + bov;
        }
    }
}

extern "C" void kernel_launch(void* const* d_in, const int* in_sizes, int n_in,
                              void* d_out, int out_size, void* d_ws, size_t ws_size,
                              hipStream_t stream){
    const float* msa = (const float*)d_in[0];
    const float* lnw = (const float*)d_in[1];
    const float* lnb = (const float*)d_in[2];
    const float* wq  = (const float*)d_in[3];
    const float* wk  = (const float*)d_in[4];
    const float* wv  = (const float*)d_in[5];
    const float* wg  = (const float*)d_in[6];
    const float* bg  = (const float*)d_in[7];
    const float* wo  = (const float*)d_in[8];
    const float* bo  = (const float*)d_in[9];
    float* out = (float*)d_out;

    const size_t SEG = (size_t)M_ROWS * DM;
    u16 *xs, *qs, *ks, *vs, *gs, *aos, *wsw;
    if (ws_size >= (6*SEG + 5*65536) * sizeof(u16)) {
        xs  = (u16*)d_ws;
        qs  = xs + SEG;
        ks  = qs + SEG;
        vs  = ks + SEG;
        gs  = vs + SEG;
        aos = gs + SEG;
        wsw = aos + SEG;
    } else {
        xs  = (u16*)d_ws;
        qs  = xs + SEG;
        gs  = qs + SEG;
        wsw = gs + SEG;
        ks  = (u16*)d_out;
        vs  = ks + SEG;
        aos = xs;                      // x dead after k_qkvg
    }

    k_wcvt<<<320, 256, 0, stream>>>(wq, wk, wv, wg, wo, wsw);
    k_ln  <<<M_ROWS/16, 256, 0, stream>>>(msa, lnw, lnb, xs);
    k_qkvg<<<dim3(M_ROWS/128, 4), 512, 0, stream>>>(xs, wsw, bg, qs, ks, vs, gs);
    k_attn<<<dim3(NH, L_RES), 512, 0, stream>>>(qs, ks, vs, gs, aos);
    k_out <<<dim3(4, 2, L_RES), 512, 0, stream>>>(aos, wsw, bo, out);
}

// Round 25
// 276.332 us; speedup vs baseline: 1.1012x; 1.1012x over previous
//
#include <hip/hip_runtime.h>

typedef unsigned short u16;
typedef unsigned int u32;
typedef __attribute__((ext_vector_type(8))) short bf16x8;
typedef __attribute__((ext_vector_type(4))) float f32x4;
typedef __attribute__((ext_vector_type(4))) u32 u32x4;

#define N_SEQ 256
#define L_RES 384
#define DM 256
#define NH 8
#define DH 32
#define M_ROWS (N_SEQ*L_RES)   // 98304
#define PANEL 8192             // N_SEQ*DH elements per (l,h) panel

// x / weights: swizzled fragment layout swz(i,k) = ((i>>4)*32+(k>>3))*128+(i&15)*8+(k&7)
// q/k/v/g/ao: per-(l,h) panels [l][h][n][d], each 16KB contiguous.

__device__ __forceinline__ u16 f2b(float f){
    unsigned u = __builtin_bit_cast(unsigned, f);
    u = u + 0x7fffu + ((u >> 16) & 1u);
    return (u16)(u >> 16);
}
__device__ __forceinline__ float b2f(u16 b){
    unsigned u = ((unsigned)b) << 16;
    return __builtin_bit_cast(float, u);
}
// pack two floats -> two bf16 in a u32 (round-to-nearest, ties up)
__device__ __forceinline__ u32 pk2(float lo, float hi){
    u32 a = (__builtin_bit_cast(u32, lo) + 0x8000u) >> 16;
    u32 b = (__builtin_bit_cast(u32, hi) + 0x8000u) & 0xffff0000u;
    return a | b;
}
// LDS bank-conflict XOR swizzle for B tiles (u16 units, keeps 16B alignment)
__device__ __forceinline__ int swzB(int a){
    return a ^ (((a>>6)&7)<<3);
}

// ---------------- Kernel 0: weights f32 -> bf16 swizzled ----------------
__global__ __launch_bounds__(256) void k_wcvt(const float* __restrict__ wq,
        const float* __restrict__ wk, const float* __restrict__ wv,
        const float* __restrict__ wg, const float* __restrict__ wo,
        u16* __restrict__ wsw){
    const int mat = blockIdx.x >> 6;
    const float* W = (mat==0)?wq:(mat==1)?wk:(mat==2)?wv:(mat==3)?wg:wo;
    const int r = ((blockIdx.x & 63)*256 + threadIdx.x)*4;
    const int col = r >> 8, k0 = r & 255;
    float4 f = *(const float4*)&W[r];
    ushort4 o;
    o.x = f2b(f.x); o.y = f2b(f.y); o.z = f2b(f.z); o.w = f2b(f.w);
    const int off = ((col>>4)*32 + (k0>>3))*128 + (col&15)*8 + (k0&7);
    *(ushort4*)&wsw[mat*65536 + off] = o;
}

// ---------------- Kernel 1: LayerNorm -> bf16 x (A-swizzled, direct store) ----------------
__global__ __launch_bounds__(256) void k_ln(const float* __restrict__ msa,
        const float* __restrict__ lnw, const float* __restrict__ lnb,
        u16* __restrict__ xo){
    const int tid = threadIdx.x;
    const int r16 = tid >> 4, lane16 = tid & 15;
    const size_t row = (size_t)blockIdx.x*16 + r16;
    const float4* src = (const float4*)(msa + row*DM + lane16*16);
    float4 a[4];
    float s = 0.f, ss = 0.f;
    #pragma unroll
    for(int j=0;j<4;j++){
        a[j] = src[j];
        s  += a[j].x + a[j].y + a[j].z + a[j].w;
        ss += a[j].x*a[j].x + a[j].y*a[j].y + a[j].z*a[j].z + a[j].w*a[j].w;
    }
    #pragma unroll
    for(int m=1;m<16;m<<=1){ s += __shfl_xor(s,m); ss += __shfl_xor(ss,m); }
    const float mu  = s*(1.f/DM);
    const float inv = rsqrtf(ss*(1.f/DM) - mu*mu + 1e-5f);
    const float4* wv4 = (const float4*)(lnw + lane16*16);
    const float4* bv4 = (const float4*)(lnb + lane16*16);
    u32 pk[8];
    #pragma unroll
    for(int j=0;j<4;j++){
        float4 w = wv4[j], b = bv4[j];
        float e0 = (a[j].x-mu)*inv*w.x + b.x;
        float e1 = (a[j].y-mu)*inv*w.y + b.y;
        float e2 = (a[j].z-mu)*inv*w.z + b.z;
        float e3 = (a[j].w-mu)*inv*w.w + b.w;
        pk[j*2]   = (u32)f2b(e0) | ((u32)f2b(e1)<<16);
        pk[j*2+1] = (u32)f2b(e2) | ((u32)f2b(e3)<<16);
    }
    u16* base = xo + (size_t)blockIdx.x*4096 + lane16*256 + r16*8;
    *(uint4*)base       = *(uint4*)&pk[0];
    *(uint4*)(base+128) = *(uint4*)&pk[4];
}

// ---------------- Kernel 2: fused Q/K/V/G projections -> [l][h][n][d] panels ----------------
// Block = (by, mat). The wave's 8 x-fragments are loaded into registers ONCE,
// then reused across the mat's four 64-col weight tiles (staged sequentially
// in one 32KB LDS buffer). x global reads /4 vs per-cb blocks.
__global__ __launch_bounds__(512) void k_qkvg(const u16* __restrict__ x,
        const u16* __restrict__ wsw, const float* __restrict__ bg,
        u16* __restrict__ qo, u16* __restrict__ ko,
        u16* __restrict__ vo, u16* __restrict__ go){
    __shared__ __align__(16) u16 Bs[16384];          // 32KB weight tile (per cg)
    const int by = blockIdx.x, mat = blockIdx.y;
    const int tid = threadIdx.x;
    const int w = tid>>6, lane = tid&63, l15 = lane&15, lq = lane>>4;
    const u16* xa = x + ((size_t)by*8 + w)*4096;      // wave's 16 rows (1 group)
    bf16x8 xf[8];
    #pragma unroll
    for(int kk=0;kk<8;kk++)
        xf[kk] = *(const bf16x8*)&xa[(kk*4+lq)*128 + l15*8];
    const float scaling = 0.17677669529663687f * 1.44269504088896f; // /sqrt(d)*log2e
    u16* O = (mat==0)?qo:(mat==1)?ko:(mat==2)?vo:go;
    const int n0 = by/3, l0 = (by%3)*128;
    const int l = l0 + w*16 + l15;                    // this lane's x-row (l coord)
    #pragma unroll 1
    for(int cg=0; cg<4; ++cg){
        const u16* wt = wsw + mat*65536 + cg*16384;
        __syncthreads();                              // prior tile reads complete
        #pragma unroll
        for(int i=0;i<4;i++)
            *(uint4*)&Bs[swzB(i*4096 + tid*8)] = *(const uint4*)&wt[i*4096 + tid*8];
        __syncthreads();
        f32x4 acc[4] = {};
        #pragma unroll
        for(int kk=0;kk<8;kk++){
            #pragma unroll
            for(int nt=0;nt<4;nt++){
                bf16x8 b = *(const bf16x8*)&Bs[swzB(nt*4096 + (kk*4+lq)*128 + l15*8)];
                acc[nt] = __builtin_amdgcn_mfma_f32_16x16x32_bf16(b,xf[kk],acc[nt],0,0,0);
            }
        }
        #pragma unroll
        for(int nt=0;nt<4;nt++){
            const int c = cg*64 + nt*16 + lq*4;       // 4 consecutive weight cols
            float v0 = acc[nt][0], v1 = acc[nt][1];
            float v2 = acc[nt][2], v3 = acc[nt][3];
            if(mat==0){ v0*=scaling; v1*=scaling; v2*=scaling; v3*=scaling; }
            else if(mat==3){
                const float4 bgv = *(const float4*)&bg[c];
                v0 = 1.f/(1.f+__expf(-(v0+bgv.x)));
                v1 = 1.f/(1.f+__expf(-(v1+bgv.y)));
                v2 = 1.f/(1.f+__expf(-(v2+bgv.z)));
                v3 = 1.f/(1.f+__expf(-(v3+bgv.w)));
            }
            uint2 ov;
            ov.x = pk2(v0, v1);
            ov.y = pk2(v2, v3);
            const int h2 = c >> 5, d = c & 31;
            *(uint2*)&O[((size_t)l*NH + h2)*PANEL + n0*32 + d] = ov;
        }
    }
}

// ---------------- Kernel 3: column attention + gate ----------------
// 8 waves x 2 interleaved 16-row streams (validated swapped-operand core).
// launch_bounds restored to (512,4) (round-24 showed natural VGPR=68 -> the
// 64-cap costs ~4 regs of minor spill but doubles wave budget; best measured).
// Defer-max (T13): skip the oacc/sp rescale when no row's chunk max grew by
// >8 (wave-uniform __all branch); P bounded by 2^8, normalized out by sp.
__global__ __launch_bounds__(512, 4) void k_attn(const u16* __restrict__ q,
        const u16* __restrict__ k, const u16* __restrict__ v,
        const u16* __restrict__ g, u16* __restrict__ ao){
    __shared__ __align__(16) u16 KFs[8192];   // K fragment-linear: 256 keys x 32 d
    __shared__ __align__(16) u16 VFs[8192];   // V^T fragment-linear, keys permuted
    const int h = blockIdx.x, l = blockIdx.y;
    const int tid = threadIdx.x;
    const size_t pbase = ((size_t)l*NH + h)*PANEL;
    const u16* kp = k + pbase;
    const u16* vp = v + pbase;
    #pragma unroll
    for(int j=0;j<2;j++){
        const int u = j*512 + tid;          // uint4 index 0..1023
        const int key = u>>2, dblk = u&3;   // d0 = dblk*8
        const uint4 tk = *(const uint4*)&kp[u*8];
        *(uint4*)&KFs[((key>>4)*4 + dblk)*128 + (key&15)*8] = tk;
        const uint4 tv = *(const uint4*)&vp[u*8];
        const int T = key>>4, gg = (key>>2)&3, r = key&3;
        const int pkey = (T>>1)*32 + ((gg&2)|(T&1))*8 + r + (((gg^T)&1)<<2);
        const int plo = (pkey>>3)*128 + (pkey&7);
        const u32 wv_[4] = {tv.x, tv.y, tv.z, tv.w};
        #pragma unroll
        for(int wd=0; wd<4; wd++){
            const int d_lo = dblk*8 + wd*2, d_hi = d_lo+1;
            VFs[((d_lo)>>4)*4096 + plo + ((d_lo)&15)*8] = (u16)(wv_[wd]&0xffff);
            VFs[((d_hi)>>4)*4096 + plo + ((d_hi)&15)*8] = (u16)(wv_[wd]>>16);
        }
    }
    __syncthreads();
    const int w = tid>>6, lane = tid&63;
    const int l15 = lane&15, lq = lane>>4;
    const int lodd = lq & 1;
    const u16* qp = q + pbase;
    const u16* gp = g + pbase;
    u16* aop = ao + pbase;
    const int q0a = w*32, q0b = w*32 + 16;
    const bf16x8 bqA = *(const bf16x8*)&qp[(q0a+l15)*32 + lq*8];
    const bf16x8 bqB = *(const bf16x8*)&qp[(q0b+l15)*32 + lq*8];
    float mA = -1e30f, spA = 0.f;
    float mB = -1e30f, spB = 0.f;
    f32x4 oaccA[2] = {}, oaccB[2] = {};
    #pragma unroll
    for(int ch=0; ch<4; ch++){
        f32x4 sA[4], sB[4];
        #pragma unroll
        for(int tt=0;tt<4;tt++){
            bf16x8 ak = *(const bf16x8*)&KFs[((ch*4+tt)*4 + lq)*128 + l15*8];
            f32x4 z = {};
            sA[tt] = __builtin_amdgcn_mfma_f32_16x16x32_bf16(ak,bqA,z,0,0,0);
            f32x4 z2 = {};
            sB[tt] = __builtin_amdgcn_mfma_f32_16x16x32_bf16(ak,bqB,z2,0,0,0);
        }
        float cmA = fmaxf(fmaxf(fmaxf(sA[0][0],sA[0][1]),fmaxf(sA[0][2],sA[0][3])),
                   fmaxf(fmaxf(fmaxf(sA[1][0],sA[1][1]),fmaxf(sA[1][2],sA[1][3])),
                   fmaxf(fmaxf(fmaxf(sA[2][0],sA[2][1]),fmaxf(sA[2][2],sA[2][3])),
                         fmaxf(fmaxf(sA[3][0],sA[3][1]),fmaxf(sA[3][2],sA[3][3])))));
        float cmB = fmaxf(fmaxf(fmaxf(sB[0][0],sB[0][1]),fmaxf(sB[0][2],sB[0][3])),
                   fmaxf(fmaxf(fmaxf(sB[1][0],sB[1][1]),fmaxf(sB[1][2],sB[1][3])),
                   fmaxf(fmaxf(fmaxf(sB[2][0],sB[2][1]),fmaxf(sB[2][2],sB[2][3])),
                         fmaxf(fmaxf(sB[3][0],sB[3][1]),fmaxf(sB[3][2],sB[3][3])))));
        cmA = fmaxf(cmA, __shfl_xor(cmA,16));
        cmB = fmaxf(cmB, __shfl_xor(cmB,16));
        cmA = fmaxf(cmA, __shfl_xor(cmA,32));
        cmB = fmaxf(cmB, __shfl_xor(cmB,32));
        // defer-max: only rescale when some row's max grew by >8 (exp2 domain)
        if(!__all((cmA <= mA + 8.f) && (cmB <= mB + 8.f))){
            const float mnA = fmaxf(mA, cmA), mnB = fmaxf(mB, cmB);
            const float scA = exp2f(mA - mnA), scB = exp2f(mB - mnB);
            mA = mnA; mB = mnB;
            spA *= scA; spB *= scB;
            #pragma unroll
            for(int i=0;i<4;i++){ oaccA[0][i]*=scA; oaccA[1][i]*=scA; oaccB[0][i]*=scB; oaccB[1][i]*=scB; }
        }
        float csA = 0.f, csB = 0.f;
        #pragma unroll
        for(int tt=0;tt<4;tt++){
            #pragma unroll
            for(int rg=0;rg<4;rg++){
                float eA = exp2f(sA[tt][rg] - mA);
                float eB = exp2f(sB[tt][rg] - mB);
                sA[tt][rg] = eA; csA += eA;
                sB[tt][rg] = eB; csB += eB;
            }
        }
        spA += csA;
        spB += csB;
        #pragma unroll
        for(int half=0; half<2; half++){
            const int mwin = ch*2 + half;
            u32 eA0 = pk2(sA[half*2][0],   sA[half*2][1]);
            u32 eA1 = pk2(sA[half*2][2],   sA[half*2][3]);
            u32 oA0 = pk2(sA[half*2+1][0], sA[half*2+1][1]);
            u32 oA1 = pk2(sA[half*2+1][2], sA[half*2+1][3]);
            u32 eB0 = pk2(sB[half*2][0],   sB[half*2][1]);
            u32 eB1 = pk2(sB[half*2][2],   sB[half*2][3]);
            u32 oB0 = pk2(sB[half*2+1][0], sB[half*2+1][1]);
            u32 oB1 = pk2(sB[half*2+1][2], sB[half*2+1][3]);
            u32 ownA0 = lodd ? oA0 : eA0,  ownA1 = lodd ? oA1 : eA1;
            u32 sndA0 = lodd ? eA0 : oA0,  sndA1 = lodd ? eA1 : oA1;
            u32 ownB0 = lodd ? oB0 : eB0,  ownB1 = lodd ? oB1 : eB1;
            u32 sndB0 = lodd ? eB0 : oB0,  sndB1 = lodd ? eB1 : oB1;
            u32 rcA0 = (u32)__shfl_xor((int)sndA0, 16);
            u32 rcB0 = (u32)__shfl_xor((int)sndB0, 16);
            u32 rcA1 = (u32)__shfl_xor((int)sndA1, 16);
            u32 rcB1 = (u32)__shfl_xor((int)sndB1, 16);
            u32x4 pwA = {ownA0, ownA1, rcA0, rcA1};
            u32x4 pwB = {ownB0, ownB1, rcB0, rcB1};
            bf16x8 pfA = __builtin_bit_cast(bf16x8, pwA);
            bf16x8 pfB = __builtin_bit_cast(bf16x8, pwB);
            #pragma unroll
            for(int nt=0;nt<2;nt++){
                bf16x8 av = *(const bf16x8*)&VFs[(nt*32 + mwin*4 + lq)*128 + l15*8];
                oaccA[nt] = __builtin_amdgcn_mfma_f32_16x16x32_bf16(av,pfA,oaccA[nt],0,0,0);
                oaccB[nt] = __builtin_amdgcn_mfma_f32_16x16x32_bf16(av,pfB,oaccB[nt],0,0,0);
            }
        }
    }
    spA += __shfl_xor(spA, 16);
    spB += __shfl_xor(spB, 16);
    spA += __shfl_xor(spA, 32);
    spB += __shfl_xor(spB, 32);
    const float rinvA = 1.f/spA, rinvB = 1.f/spB;
    const int qnA = q0a + l15, qnB = q0b + l15;
    #pragma unroll
    for(int nt=0;nt<2;nt++){
        const int c = nt*16 + lq*4;
        const uint2 glA = *(const uint2*)&gp[qnA*32 + c];
        const uint2 glB = *(const uint2*)&gp[qnB*32 + c];
        uint2 ovA, ovB;
        ovA.x = pk2(b2f((u16)(glA.x&0xffff))*oaccA[nt][0]*rinvA,
                    b2f((u16)(glA.x>>16))   *oaccA[nt][1]*rinvA);
        ovA.y = pk2(b2f((u16)(glA.y&0xffff))*oaccA[nt][2]*rinvA,
                    b2f((u16)(glA.y>>16))   *oaccA[nt][3]*rinvA);
        ovB.x = pk2(b2f((u16)(glB.x&0xffff))*oaccB[nt][0]*rinvB,
                    b2f((u16)(glB.x>>16))   *oaccB[nt][1]*rinvB);
        ovB.y = pk2(b2f((u16)(glB.y&0xffff))*oaccB[nt][2]*rinvB,
                    b2f((u16)(glB.y>>16))   *oaccB[nt][3]*rinvB);
        *(uint2*)&aop[qnA*32 + c] = ovA;
        *(uint2*)&aop[qnB*32 + c] = ovB;
    }
}

// ---------------- Kernel 4: output projection (512 thr / 8 waves x 16 rows) ----------------
__global__ __launch_bounds__(512) void k_out(const u16* __restrict__ a,
        const u16* __restrict__ wsw, const float* __restrict__ bo,
        float* __restrict__ out){
    __shared__ __align__(16) u16 Bs[16384];
    const int cb = blockIdx.x, nb = blockIdx.y, l = blockIdx.z;
    const int c0 = cb*64;
    const int tid = threadIdx.x;
    const u16* wt = wsw + 4*65536 + (c0>>4)*4096;
    #pragma unroll
    for(int i=0;i<4;i++)
        *(uint4*)&Bs[swzB(i*4096 + tid*8)] = *(const uint4*)&wt[i*4096 + tid*8];
    const int w = tid>>6, lane = tid&63, l15 = lane&15, lq = lane>>4;
    const int n0 = nb*128 + w*16;
    const size_t lbase = (size_t)l*NH*PANEL;
    bf16x8 af[8];
    #pragma unroll
    for(int kk=0;kk<8;kk++)
        af[kk] = *(const bf16x8*)&a[lbase + (size_t)kk*PANEL + (n0 + l15)*32 + lq*8];
    __syncthreads();
    f32x4 acc[4] = {};
    #pragma unroll
    for(int kk=0;kk<8;kk++){   // k = kk*32 + lq*8 -> h = kk, d = lq*8
        #pragma unroll
        for(int nt=0;nt<4;nt++){
            bf16x8 b = *(const bf16x8*)&Bs[swzB(nt*4096 + (kk*4+lq)*128 + l15*8)];
            acc[nt] = __builtin_amdgcn_mfma_f32_16x16x32_bf16(af[kk],b,acc[nt],0,0,0);
        }
    }
    #pragma unroll
    for(int nt=0;nt<4;nt++){
        const int c = c0 + nt*16 + l15;
        const float bov = bo[c];
        #pragma unroll
        for(int rg=0;rg<4;rg++){
            const int n = n0 + lq*4 + rg;
            out[((size_t)n*L_RES + l)*DM + c] = acc[nt][rg] + bov;
        }
    }
}

extern "C" void kernel_launch(void* const* d_in, const int* in_sizes, int n_in,
                              void* d_out, int out_size, void* d_ws, size_t ws_size,
                              hipStream_t stream){
    const float* msa = (const float*)d_in[0];
    const float* lnw = (const float*)d_in[1];
    const float* lnb = (const float*)d_in[2];
    const float* wq  = (const float*)d_in[3];
    const float* wk  = (const float*)d_in[4];
    const float* wv  = (const float*)d_in[5];
    const float* wg  = (const float*)d_in[6];
    const float* bg  = (const float*)d_in[7];
    const float* wo  = (const float*)d_in[8];
    const float* bo  = (const float*)d_in[9];
    float* out = (float*)d_out;

    const size_t SEG = (size_t)M_ROWS * DM;
    u16 *xs, *qs, *ks, *vs, *gs, *aos, *wsw;
    if (ws_size >= (6*SEG + 5*65536) * sizeof(u16)) {
        xs  = (u16*)d_ws;
        qs  = xs + SEG;
        ks  = qs + SEG;
        vs  = ks + SEG;
        gs  = vs + SEG;
        aos = gs + SEG;
        wsw = aos + SEG;
    } else {
        xs  = (u16*)d_ws;
        qs  = xs + SEG;
        gs  = qs + SEG;
        wsw = gs + SEG;
        ks  = (u16*)d_out;
        vs  = ks + SEG;
        aos = xs;                      // x dead after k_qkvg
    }

    k_wcvt<<<320, 256, 0, stream>>>(wq, wk, wv, wg, wo, wsw);
    k_ln  <<<M_ROWS/16, 256, 0, stream>>>(msa, lnw, lnb, xs);
    k_qkvg<<<dim3(M_ROWS/128, 4), 512, 0, stream>>>(xs, wsw, bg, qs, ks, vs, gs);
    k_attn<<<dim3(NH, L_RES), 512, 0, stream>>>(qs, ks, vs, gs, aos);
    k_out <<<dim3(4, 2, L_RES), 512, 0, stream>>>(aos, wsw, bo, out);
}